// Round 1
// 257.884 us; speedup vs baseline: 1.3109x; 1.3109x over previous
//
#include <hip/hip_runtime.h>

// Instant-NGP multires hash encoding fwd. N=1M, L=16, F=2, T=2^19.
// R5 (from R4 @ 338us):
//  - k_scatter writes sorted float4{x,y,z,bitcast(idx)} -> k_main reads its
//    points COALESCED (was: perm + scattered 12B x-gathers = ~64MB of FETCH
//    and an HBM-latency stall per point).
//  - k_colscan: 128 blocks, 8-way parallel per column (was 16 blocks, serial).
//  - NB 128->256 so hist/scatter use all 256 CUs.
//  - k_main: loader uses all 256 threads (flat index + div decompose);
//    block-uniform per-level bounds precomputed ONCE into LDS meta (was
//    recomputed per point-level); ceil = floor + (frac!=0); single corner
//    base + {0,n12}/{0,n2}/{0,1} offsets; next-point prefetch.
// Tiered on ws_size: A (~24MB, full) -> B (~8MB, R4-equivalent) -> fallback.

__constant__ float c_res[16] = {
    16.f, 18.f, 21.f, 24.f, 27.f, 32.f, 36.f, 42.f,
    48.f, 55.f, 64.f, 73.f, 84.f, 97.f, 111.f, 128.f
};

#define TMASK   0x7FFFFu
#define PRIME1  2654435761u
#define PRIME2  805459861u
#define NBUCKET 4096          // 16^3 cells
#define CACHE_N 4467          // sum over levels of max corners — exact bound

__device__ __forceinline__ int bucket_of(float x0, float x1, float x2) {
    // x*16 is EXACT in fp32 (power-of-2 scale), so cell membership is exact.
    int c0 = (int)(x0 * 16.f); c0 = c0 < 0 ? 0 : (c0 > 15 ? 15 : c0);
    int c1 = (int)(x1 * 16.f); c1 = c1 < 0 ? 0 : (c1 > 15 ? 15 : c1);
    int c2 = (int)(x2 * 16.f); c2 = c2 < 0 ? 0 : (c2 > 15 ? 15 : c2);
    return (c0 << 8) | (c1 << 4) | c2;
}

// ---- sort: per-block LDS histogram, no global atomics anywhere ----

__global__ __launch_bounds__(256)
void k_hist(const float* __restrict__ x, unsigned* __restrict__ cnt, int npts) {
    __shared__ unsigned h[NBUCKET];
    for (int i = threadIdx.x; i < NBUCKET; i += 256) h[i] = 0u;
    __syncthreads();
    int nb = gridDim.x;
    int chunk = (npts + nb - 1) / nb;
    int begin = blockIdx.x * chunk;
    int end   = begin + chunk; if (end > npts) end = npts;
    for (int i = begin + threadIdx.x; i < end; i += 256) {
        int b = bucket_of(x[3 * i], x[3 * i + 1], x[3 * i + 2]);
        atomicAdd(&h[b], 1u);          // LDS atomic — cheap
    }
    __syncthreads();
    for (int i = threadIdx.x; i < NBUCKET; i += 256)
        cnt[blockIdx.x * NBUCKET + i] = h[i];
}

// base[b][j] = sum over blocks<b of cnt[.][j]; colsum[j] = column total.
// 128 blocks x 256 threads: 32 columns/block, 8 row-groups/column.
template<int NBT>
__global__ __launch_bounds__(256)
void k_colscan(const unsigned* __restrict__ cnt, unsigned* __restrict__ base,
               unsigned* __restrict__ colsum) {
    const int RPG = NBT / 8;
    int col = blockIdx.x * 32 + (threadIdx.x & 31);
    int rg  = threadIdx.x >> 5;
    unsigned loc[RPG];
    unsigned s = 0;
    #pragma unroll
    for (int r = 0; r < RPG; ++r) {
        unsigned v = cnt[(size_t)(rg * RPG + r) * NBUCKET + col];
        loc[r] = s;                     // exclusive within row-group
        s += v;
    }
    __shared__ unsigned t[8][32];
    t[rg][threadIdx.x & 31] = s;
    __syncthreads();
    unsigned pre = 0;
    for (int g = 0; g < rg; ++g) pre += t[g][threadIdx.x & 31];
    #pragma unroll
    for (int r = 0; r < RPG; ++r)
        base[(size_t)(rg * RPG + r) * NBUCKET + col] = pre + loc[r];
    if (rg == 7) colsum[col] = pre + s;
}

// One block: exclusive scan of colsum[4096] -> starts[0..4096].
__global__ __launch_bounds__(1024)
void k_scan(const unsigned* __restrict__ colsum, unsigned* __restrict__ starts) {
    __shared__ unsigned tmp[1024];
    int t = threadIdx.x;
    unsigned v0 = colsum[4 * t + 0], v1 = colsum[4 * t + 1];
    unsigned v2 = colsum[4 * t + 2], v3 = colsum[4 * t + 3];
    unsigned s = v0 + v1 + v2 + v3;
    tmp[t] = s;
    __syncthreads();
    for (int off = 1; off < 1024; off <<= 1) {
        unsigned u = (t >= off) ? tmp[t - off] : 0u;
        __syncthreads();
        tmp[t] += u;
        __syncthreads();
    }
    unsigned excl = tmp[t] - s;
    starts[4 * t + 0] = excl;
    starts[4 * t + 1] = excl + v0;
    starts[4 * t + 2] = excl + v0 + v1;
    starts[4 * t + 3] = excl + v0 + v1 + v2;
    if (t == 1023) starts[4096] = tmp[1023];
}

// MODE 0: write sorted float4{x,y,z,bitcast(i)}.  MODE 1: write perm only.
template<int MODE>
__global__ __launch_bounds__(256)
void k_scatter(const float* __restrict__ x, const unsigned* __restrict__ base,
               const unsigned* __restrict__ starts, unsigned* __restrict__ perm,
               float4* __restrict__ xs, int npts) {
    __shared__ unsigned cur[NBUCKET];
    for (int i = threadIdx.x; i < NBUCKET; i += 256)
        cur[i] = starts[i] + base[blockIdx.x * NBUCKET + i];
    __syncthreads();
    int nb = gridDim.x;
    int chunk = (npts + nb - 1) / nb;
    int begin = blockIdx.x * chunk;
    int end   = begin + chunk; if (end > npts) end = npts;
    for (int i = begin + threadIdx.x; i < end; i += 256) {
        float x0 = x[3 * i], x1 = x[3 * i + 1], x2 = x[3 * i + 2];
        int b = bucket_of(x0, x1, x2);
        unsigned pos = atomicAdd(&cur[b], 1u);   // LDS atomic
        if constexpr (MODE == 0) {
            float4 v; v.x = x0; v.y = x1; v.z = x2;
            v.w = __uint_as_float((unsigned)i);
            xs[pos] = v;
        } else {
            perm[pos] = (unsigned)i;
        }
    }
}

// ---- main: per-cell LDS corner cache ----
// Box per level for cell i: lo=floor((i/16)*r), hi=ceil(((i+1)/16)*r).
// i*r<=2048 is fp32-exact, /16 dyadic-exact => bounds exact; fp-mul
// monotonicity => every per-point floor/ceil coord lies in [lo,hi].

template<int MODE>   // 0: sorted xs.  1: perm + scattered x (R4-compatible)
__global__ __launch_bounds__(256)
void k_main(const float4* __restrict__ xs, const float* __restrict__ x,
            const unsigned* __restrict__ perm,
            const unsigned* __restrict__ starts, const float2* __restrict__ tab,
            float4* __restrict__ out4)
{
    __shared__ float2 cache[CACHE_N];
    __shared__ int4 metaA[16];   // lo0, lo1, lo2, cbase
    __shared__ int4 metaB[16];   // n12, n2, bitcast(r), 0

    int cell = blockIdx.x;
    int startp = starts[cell], endp = starts[cell + 1];
    if (startp == endp) return;

    int ci = (cell >> 8) & 15, cj = (cell >> 4) & 15, ck = cell & 15;
    float fi0 = ci * 0.0625f, fi1 = (ci + 1) * 0.0625f;
    float fj0 = cj * 0.0625f, fj1 = (cj + 1) * 0.0625f;
    float fk0 = ck * 0.0625f, fk1 = (ck + 1) * 0.0625f;

    // -------- loader: all 256 threads, each unique corner gathered once ----
    int cbase = 0;
    #pragma unroll 1
    for (int l = 0; l < 16; ++l) {
        float r = c_res[l];
        int lo0 = (int)floorf(fi0 * r), hi0 = (int)ceilf(fi1 * r);
        int lo1 = (int)floorf(fj0 * r), hi1 = (int)ceilf(fj1 * r);
        int lo2 = (int)floorf(fk0 * r), hi2 = (int)ceilf(fk1 * r);
        int n0 = hi0 - lo0 + 1, n1 = hi1 - lo1 + 1, n2 = hi2 - lo2 + 1;
        int n12 = n1 * n2, tot = n0 * n12;
        for (int t = threadIdx.x; t < tot; t += 256) {
            int a = t / n12, rem = t - a * n12;
            int b = rem / n2, d = rem - b * n2;
            unsigned h = ((unsigned)(lo0 + a)
                        ^ ((unsigned)(lo1 + b) * PRIME1)
                        ^ ((unsigned)(lo2 + d) * PRIME2)) & TMASK;
            cache[cbase + t] = tab[h];
        }
        if (threadIdx.x == 0) {
            metaA[l] = make_int4(lo0, lo1, lo2, cbase);
            metaB[l] = make_int4(n12, n2, __float_as_int(r), 0);
        }
        cbase += tot;
    }
    __syncthreads();

    // -------- interp: all table reads from LDS, meta from LDS (uniform) ----
    auto lvl = [&](int l, float a0, float a1, float a2, float& ex, float& ey) {
        int4 mA = metaA[l];
        int4 mB = metaB[l];
        float r = __int_as_float(mB.z);
        int n12 = mB.x, n2 = mB.y;
        float s0 = a0 * r, s1 = a1 * r, s2 = a2 * r;   // lone mul == numpy
        float f0 = floorf(s0), f1 = floorf(s1), f2 = floorf(s2);
        float d0 = s0 - f0, d1 = s1 - f1, d2 = s2 - f2;
        int A0 = (int)f0 - mA.x, A1 = (int)f1 - mA.y, A2 = (int)f2 - mA.z;
        // ceil(s) = floor(s) + (s != floor(s)) for s >= 0
        int e0 = (d0 != 0.f) ? n12 : 0;
        int e1 = (d1 != 0.f) ? n2  : 0;
        int e2 = (d2 != 0.f) ? 1   : 0;
        int rA = mA.w + A0 * n12 + A1 * n2 + A2;

        float2 v0 = cache[rA];                 // 000
        float2 v1 = cache[rA + e0];            // 100
        float2 v2 = cache[rA + e1];            // 010
        float2 v3 = cache[rA + e2];            // 001
        float2 v4 = cache[rA + e0 + e1];       // 110
        float2 v5 = cache[rA + e0 + e2];       // 101
        float2 v6 = cache[rA + e1 + e2];       // 011
        float2 v7 = cache[rA + e0 + e1 + e2];  // 111

        float u0 = 1.f - d0, u1 = 1.f - d1, u2 = 1.f - d2;
        float pa = u1 * u2, pb = d1 * u2, pc = u1 * d2, pe = d1 * d2;
        float w0 = u0 * pa, w1 = d0 * pa, w2 = u0 * pb, w3 = u0 * pc;
        float w4 = d0 * pb, w5 = d0 * pc, w6 = u0 * pe, w7 = d0 * pe;

        float rx = v0.x * w0, ry = v0.y * w0;
        rx += v1.x * w1;  ry += v1.y * w1;
        rx += v2.x * w2;  ry += v2.y * w2;
        rx += v3.x * w3;  ry += v3.y * w3;
        rx += v4.x * w4;  ry += v4.y * w4;
        rx += v5.x * w5;  ry += v5.y * w5;
        rx += v6.x * w6;  ry += v6.y * w6;
        rx += v7.x * w7;  ry += v7.y * w7;
        ex = rx; ey = ry;
    };

    auto fetch = [&](int s, float& a0, float& a1, float& a2, unsigned& pp) {
        if constexpr (MODE == 0) {
            float4 v = xs[s];
            a0 = v.x; a1 = v.y; a2 = v.z; pp = __float_as_uint(v.w);
        } else {
            pp = perm[s];
            a0 = x[3 * pp]; a1 = x[3 * pp + 1]; a2 = x[3 * pp + 2];
        }
    };

    int sp = startp + (int)threadIdx.x;
    if (sp >= endp) return;
    float x0, x1, x2; unsigned p;
    fetch(sp, x0, x1, x2, p);
    while (true) {
        int spn = sp + 256;
        bool more = spn < endp;
        float nx0, nx1, nx2; unsigned np;
        if (more) fetch(spn, nx0, nx1, nx2, np);   // prefetch next point

        #pragma unroll 1
        for (int lp = 0; lp < 8; ++lp) {
            float4 o;
            lvl(2 * lp,     x0, x1, x2, o.x, o.y);
            lvl(2 * lp + 1, x0, x1, x2, o.z, o.w);
            out4[(size_t)p * 8 + lp] = o;
        }

        if (!more) break;
        x0 = nx0; x1 = nx1; x2 = nx2; p = np;
        sp = spn;
    }
}

// Fallback (R1) if ws too small.
__global__ __launch_bounds__(256, 8)
void k_fallback(const float* __restrict__ x, const float2* __restrict__ tab,
                float2* __restrict__ out, int total) {
    int tid = blockIdx.x * 256 + threadIdx.x;
    if (tid >= total) return;
    int p = tid >> 4, l = tid & 15;
    float r = c_res[l];
    float s0 = x[3*p] * r, s1 = x[3*p+1] * r, s2 = x[3*p+2] * r;
    float f0 = floorf(s0), f1 = floorf(s1), f2 = floorf(s2);
    float d0 = s0 - f0, d1 = s1 - f1, d2 = s2 - f2;
    unsigned A0 = (unsigned)(int)f0, B0 = (unsigned)(int)ceilf(s0);
    unsigned A1 = (unsigned)(int)f1 * PRIME1, B1 = (unsigned)(int)ceilf(s1) * PRIME1;
    unsigned A2 = (unsigned)(int)f2 * PRIME2, B2 = (unsigned)(int)ceilf(s2) * PRIME2;
    unsigned h0=(A0^A1^A2)&TMASK, h1=(B0^A1^A2)&TMASK, h2=(A0^B1^A2)&TMASK;
    unsigned h3=(A0^A1^B2)&TMASK, h4=(B0^B1^A2)&TMASK, h5=(B0^A1^B2)&TMASK;
    unsigned h6=(A0^B1^B2)&TMASK, h7=(B0^B1^B2)&TMASK;
    float2 v0=tab[h0],v1=tab[h1],v2=tab[h2],v3=tab[h3];
    float2 v4=tab[h4],v5=tab[h5],v6=tab[h6],v7=tab[h7];
    float u0=1.f-d0,u1=1.f-d1,u2=1.f-d2;
    float ex = v0.x*(u0*u1*u2), ey = v0.y*(u0*u1*u2);
    ex += v1.x*(d0*u1*u2); ey += v1.y*(d0*u1*u2);
    ex += v2.x*(u0*d1*u2); ey += v2.y*(u0*d1*u2);
    ex += v3.x*(u0*u1*d2); ey += v3.y*(u0*u1*d2);
    ex += v4.x*(d0*d1*u2); ey += v4.y*(d0*d1*u2);
    ex += v5.x*(d0*u1*d2); ey += v5.y*(d0*u1*d2);
    ex += v6.x*(u0*d1*d2); ey += v6.y*(u0*d1*d2);
    ex += v7.x*(d0*d1*d2); ey += v7.y*(d0*d1*d2);
    float2 o; o.x = ex; o.y = ey; out[tid] = o;
}

extern "C" void kernel_launch(void* const* d_in, const int* in_sizes, int n_in,
                              void* d_out, int out_size, void* d_ws, size_t ws_size,
                              hipStream_t stream)
{
    const float*  x   = (const float*)d_in[0];
    const float2* tab = (const float2*)d_in[1];
    int npts = in_sizes[0] / 3;

    // ---- Tier A: NB=256, sorted-float4 payload (~24 MB ws) ----
    {
        const int NBA = 256;
        size_t off_cnt    = 0;
        size_t off_base   = off_cnt    + (size_t)NBA * NBUCKET * 4;   // 4 MB
        size_t off_colsum = off_base   + (size_t)NBA * NBUCKET * 4;   // 4 MB
        size_t off_starts = off_colsum + (size_t)NBUCKET * 4;
        size_t off_xs     = (off_starts + (size_t)(NBUCKET + 1) * 4 + 63)
                            & ~(size_t)63;
        size_t need       = off_xs + (size_t)npts * 16;
        if (ws_size >= need) {
            unsigned* cnt    = (unsigned*)((char*)d_ws + off_cnt);
            unsigned* base   = (unsigned*)((char*)d_ws + off_base);
            unsigned* colsum = (unsigned*)((char*)d_ws + off_colsum);
            unsigned* starts = (unsigned*)((char*)d_ws + off_starts);
            float4*   xs     = (float4*)  ((char*)d_ws + off_xs);

            k_hist        <<<NBA, 256, 0, stream>>>(x, cnt, npts);
            k_colscan<256><<<NBUCKET / 32, 256, 0, stream>>>(cnt, base, colsum);
            k_scan        <<<1, 1024, 0, stream>>>(colsum, starts);
            k_scatter<0>  <<<NBA, 256, 0, stream>>>(x, base, starts,
                                                    nullptr, xs, npts);
            k_main<0>     <<<NBUCKET, 256, 0, stream>>>(xs, x, nullptr, starts,
                                                        tab, (float4*)d_out);
            return;
        }
    }

    // ---- Tier B: NB=128, perm-only (R4 footprint, ~8 MB ws) ----
    {
        const int NBB = 128;
        size_t off_cnt    = 0;
        size_t off_base   = off_cnt    + (size_t)NBB * NBUCKET * 4;   // 2 MB
        size_t off_colsum = off_base   + (size_t)NBB * NBUCKET * 4;   // 2 MB
        size_t off_starts = off_colsum + (size_t)NBUCKET * 4;
        size_t off_perm   = (off_starts + (size_t)(NBUCKET + 1) * 4 + 63)
                            & ~(size_t)63;
        size_t need       = off_perm + (size_t)npts * 4;
        if (ws_size >= need) {
            unsigned* cnt    = (unsigned*)((char*)d_ws + off_cnt);
            unsigned* base   = (unsigned*)((char*)d_ws + off_base);
            unsigned* colsum = (unsigned*)((char*)d_ws + off_colsum);
            unsigned* starts = (unsigned*)((char*)d_ws + off_starts);
            unsigned* perm   = (unsigned*)((char*)d_ws + off_perm);

            k_hist        <<<NBB, 256, 0, stream>>>(x, cnt, npts);
            k_colscan<128><<<NBUCKET / 32, 256, 0, stream>>>(cnt, base, colsum);
            k_scan        <<<1, 1024, 0, stream>>>(colsum, starts);
            k_scatter<1>  <<<NBB, 256, 0, stream>>>(x, base, starts,
                                                    perm, nullptr, npts);
            k_main<1>     <<<NBUCKET, 256, 0, stream>>>(nullptr, x, perm, starts,
                                                        tab, (float4*)d_out);
            return;
        }
    }

    // ---- fallback ----
    int total = npts * 16;
    k_fallback<<<(total + 255) / 256, 256, 0, stream>>>(
        x, tab, (float2*)d_out, total);
}